// Round 4
// baseline (139.535 us; speedup 1.0000x reference)
//
#include <hip/hip_runtime.h>
#include <hip/hip_bf16.h>

// Problem constants
constexpr int Bb  = 8;
constexpr int Ss  = 2048;
constexpr int Ee  = 128;
constexpr int Hh  = 8;
constexpr int HSs = 16;
constexpr int QKVSZ = Bb * Hh * Ss * HSs;  // 2,097,152 elements per tensor

typedef _Float16 f16;
typedef __attribute__((ext_vector_type(8)))  _Float16 f16x8;   // 8 f16 = 4 VGPRs
typedef __attribute__((ext_vector_type(16))) float f32x16;

constexpr float QSCALE = 5.770780163555854f;  // 4 * log2(e); folded into stored k

// RTZ packed fp32x2 -> fp16x2
__device__ __forceinline__ unsigned pack_rtz(float lo, float hi) {
    union { __fp16 __attribute__((ext_vector_type(2))) h; unsigned u; } c;
    c.h = __builtin_amdgcn_cvt_pkrtz(lo, hi);
    return c.u;
}
// RNE pair pack
__device__ __forceinline__ unsigned pack_rne(float lo, float hi) {
    union { __attribute__((ext_vector_type(2))) _Float16 h; unsigned u; } c;
    c.h[0] = (f16)lo; c.h[1] = (f16)hi;
    return c.u;
}

// max of 16 floats, max3-friendly groupings (ISel fuses fmax(fmax(a,b),c) -> v_max3_f32)
__device__ __forceinline__ float vmax16(const f32x16& v) {
    float a = fmaxf(fmaxf(v[0],  v[1]),  v[2]);
    float b = fmaxf(fmaxf(v[3],  v[4]),  v[5]);
    float c = fmaxf(fmaxf(v[6],  v[7]),  v[8]);
    float d = fmaxf(fmaxf(v[9],  v[10]), v[11]);
    float e = fmaxf(fmaxf(v[12], v[13]), v[14]);
    float g = fmaxf(fmaxf(a, b), c);
    float h = fmaxf(fmaxf(d, e), v[15]);
    return fmaxf(g, h);
}

// fp32x8 -> f16x8 (RNE) from two float4s
__device__ __forceinline__ f16x8 cvt8(const float4& w0, const float4& w1) {
    union { f16x8 v; unsigned u[4]; } wf;
    wf.u[0] = pack_rne(w0.x, w0.y); wf.u[1] = pack_rne(w0.z, w0.w);
    wf.u[2] = pack_rne(w1.x, w1.y); wf.u[3] = pack_rne(w1.z, w1.w);
    return wf.v;
}

// ---------------------------------------------------------------------------
// Kernel A: FUSED Q/K/V projection, 8 waves (512 thr), inline fp32->f16 W cvt.
// X staged fp32->f16 via LDS ONCE; the same per-lane 16B fragment serves as
// B-operand (waves 0-3, q/k, SWAPPED operand order) and A-operand (waves 4-7,
// v, original order) -- A and B per-lane layouts are identical.
//   waves 0-3 (wid=0..3): Q then K for channel group wid, C[c][s] layout ->
//     channels in regs, rows in lanes -> uint2 (4 x f16 consecutive d) stores.
//   waves 4-7: V group wid-4, original order C[s][c]; v written in A-FRAG
//     ORDER with the key-slot PERMUTATION matching the QK^T C-layout:
//     in-chunk key p = 4h' + a + 8b' -> va-group p>>4, lane-half h'=(p>>2)&1,
//     element j = 4*((p>>3)&1) + (p&3). Plus pad rows m=16..31 (m==16 -> 1.0
//     ones-row for the l-accumulator trick).
// ---------------------------------------------------------------------------
__global__ __launch_bounds__(512, 4) void qkv_kernel(
    const float* __restrict__ x,
    const float* __restrict__ Wq, const float* __restrict__ Wk,
    const float* __restrict__ Wv,
    f16* __restrict__ qo, f16* __restrict__ ko, f16* __restrict__ vo)
{
    constexpr int LDW = 136;                      // padded row (f16), b128-aligned
    __shared__ __align__(16) f16 Xs[32 * LDW];    // 8.7 KB

    const int rowbase = blockIdx.x * 32;

    // stage X tile (32 x 128) fp32 -> f16, coalesced float4 reads (ONCE)
    for (int idx = threadIdx.x; idx < 32 * 32; idx += 512) {
        const int r = idx >> 5, cp = idx & 31;
        float4 v = *(const float4*)(x + (size_t)(rowbase + r) * Ee + cp * 4);
        union { f16 h[4]; uint2 u; } cv;
        cv.h[0] = (f16)v.x; cv.h[1] = (f16)v.y; cv.h[2] = (f16)v.z; cv.h[3] = (f16)v.w;
        *(uint2*)&Xs[r * LDW + cp * 4] = cv.u;
    }
    __syncthreads();

    const int wid = threadIdx.x >> 6, lane = threadIdx.x & 63;
    const int h = lane >> 5, n31 = lane & 31;

    // per-lane 16B X fragments (same bytes serve as A- or B-operand)
    f16x8 Xf[8];
#pragma unroll
    for (int t = 0; t < 8; ++t)
        Xf[t] = *(const f16x8*)&Xs[n31 * LDW + 16 * t + 8 * h];

    const int b = rowbase >> 11;
    const int s0 = rowbase & 2047;

    if (wid < 4) {
        // ---- Q and K, swapped operands: C[c][s], channels in regs ----
        const int s = s0 + n31;
#pragma unroll
        for (int mat = 0; mat < 2; ++mat) {
            const float* W = (mat == 0) ? Wq : Wk;
            const float* wr32 = W + (size_t)(wid * 32 + n31) * Ee + 8 * h;
            f32x16 acc = {};
#pragma unroll
            for (int t = 0; t < 8; ++t) {
                float4 w0 = *(const float4*)(wr32 + 16 * t);
                float4 w1 = *(const float4*)(wr32 + 16 * t + 4);
                acc = __builtin_amdgcn_mfma_f32_32x32x16_f16(cvt8(w0, w1), Xf[t], acc, 0, 0, 0);
            }
            f16* dst = (mat == 0) ? qo : ko;
            const float scale = (mat == 1) ? QSCALE : 1.f;
#pragma unroll
            for (int rq = 0; rq < 4; ++rq) {
                const int cbase = wid * 32 + 8 * rq + 4 * h;   // 4 consecutive c
                const int head = cbase >> 4, dbase = cbase & 15;
                union { f16 hv[4]; uint2 u; } pk4;
#pragma unroll
                for (int i = 0; i < 4; ++i) pk4.hv[i] = (f16)(acc[4 * rq + i] * scale);
                *(uint2*)(dst + ((size_t)(b * Hh + head) * Ss + s) * HSs + dbase) = pk4.u;
            }
        }
    } else {
        // ---- V, original order: C[s][c], key-slots in regs ----
        const int g = wid - 4;
        const int c = g * 32 + n31;               // channel = head*16 + d
        const int head = c >> 4, d = c & 15;
        const int bh = b * Hh + head;
        const int it = s0 >> 6, g0 = (s0 >> 4) & 3;
        const float* wr32 = Wv + (size_t)c * Ee + 8 * h;
        f32x16 acc = {};
#pragma unroll
        for (int t = 0; t < 8; ++t) {
            float4 w0 = *(const float4*)(wr32 + 16 * t);
            float4 w1 = *(const float4*)(wr32 + 16 * t + 4);
            acc = __builtin_amdgcn_mfma_f32_32x32x16_f16(Xf[t], cvt8(w0, w1), acc, 0, 0, 0);
        }
        f16* vb = vo + (size_t)bh * 65536 + it * 2048;
#pragma unroll
        for (int rq = 0; rq < 4; ++rq) {
            union { f16 hv[4]; uint2 u; } pk4;
#pragma unroll
            for (int i = 0; i < 4; ++i) pk4.hv[i] = (f16)acc[4 * rq + i];
            // permuted k-slot placement: h' = h, b' = rq&1, j = 4*b' + a
            *(uint2*)(vb + (g0 + (rq >> 1)) * 512 + (d + 32 * h) * 8 + 4 * (rq & 1)) = pk4.u;
        }

        // pad rows m=16..31 for this block's two 16-key groups, all 8 heads:
        // m==16 -> 1.0 (l-accumulator row), else 0. All k-slots equal.
        for (int i = threadIdx.x - 256; i < 512; i += 256) {
            const int gp = i >> 8, hd = (i >> 5) & 7, cc = i & 31;
            const int lanep = (cc < 16) ? 16 + cc : 32 + cc;
            const unsigned one2 = 0x3C003C00u;
            uint4 val = ((cc & 15) == 0) ? (uint4){one2, one2, one2, one2}
                                         : (uint4){0, 0, 0, 0};
            *(uint4*)(vo + (size_t)(b * Hh + hd) * 65536 + it * 2048
                      + (g0 + gp) * 512 + lanep * 8) = val;
        }
    }
}

// ---------------------------------------------------------------------------
// Kernel B: flash attention PASS 1, SPLIT-K x2. 2048 blocks x 4 waves,
// NO LDS, NO BARRIERS -> 8192 wave-tasks (2x occupancy ceiling vs unsplit).
// Each wave: 32 queries x 1024 keys (16 chunk iters). Same verified inner
// loop (V key-slot permutation = zero-shuffle P; cinit = -m folded into QK^T
// C-operand; defer-max THR=8; in-place operand prefetch) PLUS dual
// accumulators (accA/accB) halving the serial PV MFMA chain.
// Output: per-half NORMALIZED O (f16, [half][bh][qt][q][16]) and (m,l) f32.
// blk decode: b=blk&7 (XCD-local), qt=(blk>>3)&63, hg=(blk>>9)&1, half=blk>>10.
// ---------------------------------------------------------------------------
__global__ __launch_bounds__(256, 4) void attn_pass1(
    const f16* __restrict__ qg, const f16* __restrict__ kg,
    const f16* __restrict__ vg, f16* __restrict__ po, float* __restrict__ pml)
{
    const int blk  = blockIdx.x;                   // 2048
    const int b    = blk & 7;
    const int qt   = (blk >> 3) & 63;
    const int hg   = (blk >> 9) & 1;
    const int half = (blk >> 10) & 1;
    const int wid  = threadIdx.x >> 6;             // 0..3
    const int lane = threadIdx.x & 63;
    const int h    = lane >> 5;
    const int q31  = lane & 31;
    const int head = hg * 4 + wid;
    const int bh   = b * Hh + head;
    const int qbase = qt * 32;

    // Q B-frag (QSCALE folded into k)
    const f16x8 qf = *(const f16x8*)(qg + ((size_t)bh * Ss + qbase + q31) * HSs + 8 * h);

    // per-lane streaming pointers into this half's 1024 keys
    const f16* pk = kg + (size_t)bh * Ss * HSs + half * 16384 + q31 * 16 + 8 * h;
    const f16* pv = vg + (size_t)bh * 65536 + half * 32768 + lane * 8;

    // current-chunk operands
    f16x8 ka0 = *(const f16x8*)pk;
    f16x8 ka1 = *(const f16x8*)(pk + 512);
    f16x8 va0 = *(const f16x8*)(pv);
    f16x8 va1 = *(const f16x8*)(pv + 512);
    f16x8 va2 = *(const f16x8*)(pv + 1024);
    f16x8 va3 = *(const f16x8*)(pv + 1536);

    f32x16 accA = {};
    f32x16 accB = {};
    f32x16 cinit = {};                 // broadcast -m; st = s - m straight from MFMA

    constexpr int NIT = (Ss / 2) / 64; // 16
    for (int it = 0; it < NIT; ++it) {
        // S^T - m = K x Q^T + cinit for key groups 0..31, 32..63
        f32x16 st0 = __builtin_amdgcn_mfma_f32_32x32x16_f16(ka0, qf, cinit, 0, 0, 0);
        f32x16 st1 = __builtin_amdgcn_mfma_f32_32x32x16_f16(ka1, qf, cinit, 0, 0, 0);

        // K operands dead: load next chunk in-place (used next iteration)
        if (it + 1 < NIT) {
            pk += 1024;
            ka0 = *(const f16x8*)pk;
            ka1 = *(const f16x8*)(pk + 512);
        }

        // chunk max relative to m (max3 tree + one xor32) -> per-query (lane-pair)
        float mx = fmaxf(vmax16(st0), vmax16(st1));
        mx = fmaxf(mx, __shfl_xor(mx, 32, 64));

        // deferred rescale: only when some query grew past m + 8
        if (__any(mx > 8.f)) {
            const float delta = fmaxf(mx, 0.f);
            const float corr  = __builtin_amdgcn_exp2f(-delta);
#pragma unroll
            for (int r = 0; r < 9; ++r) { accA[r] *= corr; accB[r] *= corr; }
#pragma unroll
            for (int t = 0; t < 16; ++t) { st0[t] -= delta; st1[t] -= delta; }
#pragma unroll
            for (int r = 0; r < 16; ++r) cinit[r] -= delta;
        }

        // p = exp2(st) packed to f16; key-slot permutation => direct renames
        union { unsigned u[4]; f16x8 v; } B1, B2, B3, B4;
#pragma unroll
        for (int r = 0; r < 4; ++r) {
            B1.u[r] = pack_rtz(__builtin_amdgcn_exp2f(st0[2 * r]),
                               __builtin_amdgcn_exp2f(st0[2 * r + 1]));
            B2.u[r] = pack_rtz(__builtin_amdgcn_exp2f(st0[8 + 2 * r]),
                               __builtin_amdgcn_exp2f(st0[9 + 2 * r]));
            B3.u[r] = pack_rtz(__builtin_amdgcn_exp2f(st1[2 * r]),
                               __builtin_amdgcn_exp2f(st1[2 * r + 1]));
            B4.u[r] = pack_rtz(__builtin_amdgcn_exp2f(st1[8 + 2 * r]),
                               __builtin_amdgcn_exp2f(st1[9 + 2 * r]));
        }

        // O^T += V'^T x P^T; dual accumulators halve the serial MFMA chain.
        // (ones-row at m=16 accumulates l into accA[8]/accB[8])
        __builtin_amdgcn_s_setprio(1);
        accA = __builtin_amdgcn_mfma_f32_32x32x16_f16(va0, B1.v, accA, 0, 0, 0);
        accB = __builtin_amdgcn_mfma_f32_32x32x16_f16(va1, B2.v, accB, 0, 0, 0);
        accA = __builtin_amdgcn_mfma_f32_32x32x16_f16(va2, B3.v, accA, 0, 0, 0);
        accB = __builtin_amdgcn_mfma_f32_32x32x16_f16(va3, B4.v, accB, 0, 0, 0);
        __builtin_amdgcn_s_setprio(0);

        // V operands dead: load next chunk in-place
        if (it + 1 < NIT) {
            pv += 2048;
            va0 = *(const f16x8*)(pv);
            va1 = *(const f16x8*)(pv + 512);
            va2 = *(const f16x8*)(pv + 1024);
            va3 = *(const f16x8*)(pv + 1536);
        }
    }

    // l: ones-row hits accA[8]/accB[8] on h=0 lanes; h=1 partner via shfl
    float l = accA[8] + accB[8];
    l += __shfl_xor(l, 32, 64);
    const float inv = 1.f / l;
    const float m = -cinit[0];

    // normalized per-half O -> f16 partials [half][bh][qt][q][16]
    f16* pb = po + ((((size_t)half * 64 + bh) * 64 + qt) * 32 + q31) * 16;
    uint2 w0 = { pack_rne((accA[0] + accB[0]) * inv, (accA[1] + accB[1]) * inv),
                 pack_rne((accA[2] + accB[2]) * inv, (accA[3] + accB[3]) * inv) };
    uint2 w1 = { pack_rne((accA[4] + accB[4]) * inv, (accA[5] + accB[5]) * inv),
                 pack_rne((accA[6] + accB[6]) * inv, (accA[7] + accB[7]) * inv) };
    *(uint2*)(pb + 4 * h)     = w0;
    *(uint2*)(pb + 8 + 4 * h) = w1;

    if (h == 0) {
        float2 ml = { m, l };
        *(float2*)(pml + ((((size_t)half * 64 + bh) * 64 + qt) * 32 + q31) * 2) = ml;
    }
}

// ---------------------------------------------------------------------------
// Kernel C: merge (flash combine of the two K-halves) + output projection.
// 512 blocks (b,qt) x 8 waves. Wave wid = head: lanes (q31,h) read the two
// halves' normalized O[q][8h..8h+7] (coalesced 16B) + (m,l) pairs, combine
// O = w1*O1 + w2*O2 with w_i = l_i*exp2(m_i-M)/sum, write f16 to LDS tile
// [32 x 136]; one barrier; waves 0..3 run the proj (K=128, 8 MFMA, inline
// fp32->f16 Wp cvt), fp32 + bias stores.
// ---------------------------------------------------------------------------
__global__ __launch_bounds__(512, 4) void merge_proj(
    const f16* __restrict__ po, const float* __restrict__ pml,
    const float* __restrict__ wp32, const float* __restrict__ bp,
    float* __restrict__ out)
{
    constexpr int LDW = 136;
    __shared__ __align__(16) f16 Os[32 * LDW];    // 8.7 KB
    constexpr size_t HALF_O  = (size_t)64 * 64 * 32 * 16;  // po elems per half
    constexpr size_t HALF_ML = (size_t)64 * 64 * 32 * 2;   // pml floats per half

    const int b    = blockIdx.x & 7;
    const int qt   = blockIdx.x >> 3;
    const int qbase = qt * 32;
    const int wid  = threadIdx.x >> 6;             // head
    const int lane = threadIdx.x & 63;
    const int h    = lane >> 5;
    const int q31  = lane & 31;
    const int bh   = b * Hh + wid;

    // ---- merge: lane handles q=q31, channels wid*16 + 8h .. +7 ----
    const size_t ob = (((size_t)bh * 64 + qt) * 32 + q31) * 16 + 8 * h;
    f16x8 o1 = *(const f16x8*)(po + ob);
    f16x8 o2 = *(const f16x8*)(po + HALF_O + ob);
    const size_t mb = (((size_t)bh * 64 + qt) * 32 + q31) * 2;
    float2 ml1 = *(const float2*)(pml + mb);
    float2 ml2 = *(const float2*)(pml + HALF_ML + mb);

    const float M  = fmaxf(ml1.x, ml2.x);
    float w1 = ml1.y * __builtin_amdgcn_exp2f(ml1.x - M);
    float w2 = ml2.y * __builtin_amdgcn_exp2f(ml2.x - M);
    const float winv = 1.f / (w1 + w2);
    w1 *= winv; w2 *= winv;

    float om[8];
#pragma unroll
    for (int j = 0; j < 8; ++j) om[j] = (float)o1[j] * w1 + (float)o2[j] * w2;
    uint2 lo = { pack_rne(om[0], om[1]), pack_rne(om[2], om[3]) };
    uint2 hi = { pack_rne(om[4], om[5]), pack_rne(om[6], om[7]) };
    f16* orow = &Os[q31 * LDW + wid * HSs + 8 * h];
    *(uint2*)(orow)     = lo;
    *(uint2*)(orow + 4) = hi;
    __syncthreads();

    if (wid >= 4) return;

    // ---- output projection: waves 0..3, one 32-channel group each ----
    f16x8 A[8];
#pragma unroll
    for (int t = 0; t < 8; ++t)
        A[t] = *(const f16x8*)&Os[q31 * LDW + 16 * t + 8 * h];

    const int e = wid * 32 + q31;
    const float* wr32 = wp32 + (size_t)e * Ee + 8 * h;
    f32x16 acc2 = {};
#pragma unroll
    for (int t = 0; t < 8; ++t) {
        float4 w0 = *(const float4*)(wr32 + 16 * t);
        float4 w1v = *(const float4*)(wr32 + 16 * t + 4);
        acc2 = __builtin_amdgcn_mfma_f32_32x32x16_f16(A[t], cvt8(w0, w1v), acc2, 0, 0, 0);
    }

    const float bias = bp[e];
#pragma unroll
    for (int r = 0; r < 16; ++r) {
        const int R = qbase + (r & 3) + 8 * (r >> 2) + 4 * h;
        out[((size_t)b * Ss + R) * Ee + e] = acc2[r] + bias;
    }
}

// ---------------------------------------------------------------------------
extern "C" void kernel_launch(void* const* d_in, const int* in_sizes, int n_in,
                              void* d_out, int out_size, void* d_ws, size_t ws_size,
                              hipStream_t stream)
{
    const float* x  = (const float*)d_in[0];
    const float* Wk = (const float*)d_in[1];
    const float* Wq = (const float*)d_in[2];
    const float* Wv = (const float*)d_in[3];
    const float* Wp = (const float*)d_in[4];
    const float* bp = (const float*)d_in[5];
    float* out = (float*)d_out;

    f16* ws = (f16*)d_ws;
    f16* qh = ws;                              // 2M f16
    f16* kh = ws + (size_t)QKVSZ;              // 2M
    f16* vh = ws + (size_t)2 * QKVSZ;          // 4M (A-frag order + pad rows, permuted k-slots)
    f16* po = ws + (size_t)4 * QKVSZ;          // 4M f16: partial O, 2 halves
    float* pml = (float*)(ws + (size_t)6 * QKVSZ);  // 0.5M f32: (m,l) pairs, 2 halves

    qkv_kernel<<<Bb * Ss / 32, 512, 0, stream>>>(x, Wq, Wk, Wv, qh, kh, vh);
    attn_pass1<<<2 * 2 * 64 * 8, 256, 0, stream>>>(qh, kh, vh, po, pml);
    merge_proj<<<Bb * Ss / 32, 512, 0, stream>>>(po, pml, Wp, bp, out);
}

// Round 6
// 133.730 us; speedup vs baseline: 1.0434x; 1.0434x over previous
//
#include <hip/hip_runtime.h>
#include <hip/hip_bf16.h>

// Problem constants
constexpr int Bb  = 8;
constexpr int Ss  = 2048;
constexpr int Ee  = 128;
constexpr int Hh  = 8;
constexpr int HSs = 16;
constexpr int QKVSZ = Bb * Hh * Ss * HSs;  // 2,097,152 elements per tensor

typedef _Float16 f16;
typedef __attribute__((ext_vector_type(8)))  _Float16 f16x8;   // 8 f16 = 4 VGPRs
typedef __attribute__((ext_vector_type(16))) float f32x16;

constexpr float QSCALE = 5.770780163555854f;  // 4 * log2(e); folded into stored k

// RTZ packed fp32x2 -> fp16x2
__device__ __forceinline__ unsigned pack_rtz(float lo, float hi) {
    union { __fp16 __attribute__((ext_vector_type(2))) h; unsigned u; } c;
    c.h = __builtin_amdgcn_cvt_pkrtz(lo, hi);
    return c.u;
}
// RNE pair pack
__device__ __forceinline__ unsigned pack_rne(float lo, float hi) {
    union { __attribute__((ext_vector_type(2))) _Float16 h; unsigned u; } c;
    c.h[0] = (f16)lo; c.h[1] = (f16)hi;
    return c.u;
}

// max of 16 floats, max3-friendly groupings (ISel fuses fmax(fmax(a,b),c) -> v_max3_f32)
__device__ __forceinline__ float vmax16(const f32x16& v) {
    float a = fmaxf(fmaxf(v[0],  v[1]),  v[2]);
    float b = fmaxf(fmaxf(v[3],  v[4]),  v[5]);
    float c = fmaxf(fmaxf(v[6],  v[7]),  v[8]);
    float d = fmaxf(fmaxf(v[9],  v[10]), v[11]);
    float e = fmaxf(fmaxf(v[12], v[13]), v[14]);
    float g = fmaxf(fmaxf(a, b), c);
    float h = fmaxf(fmaxf(d, e), v[15]);
    return fmaxf(g, h);
}

// fp32x8 -> f16x8 (RNE) from two float4s
__device__ __forceinline__ f16x8 cvt8(const float4& w0, const float4& w1) {
    union { f16x8 v; unsigned u[4]; } wf;
    wf.u[0] = pack_rne(w0.x, w0.y); wf.u[1] = pack_rne(w0.z, w0.w);
    wf.u[2] = pack_rne(w1.x, w1.y); wf.u[3] = pack_rne(w1.z, w1.w);
    return wf.v;
}

// ---------------------------------------------------------------------------
// Kernel A: FUSED Q/K/V projection, 8 waves (512 thr), inline fp32->f16 W cvt.
// X staged fp32->f16 via LDS ONCE; the same per-lane 16B fragment serves as
// B-operand (waves 0-3, q/k, SWAPPED operand order) and A-operand (waves 4-7,
// v, original order) -- A and B per-lane layouts are identical.
//   waves 0-3 (wid=0..3): Q then K for channel group wid, C[c][s] layout ->
//     channels in regs, rows in lanes -> uint2 (4 x f16 consecutive d) stores.
//   waves 4-7: V group wid-4, original order C[s][c]; v written in A-FRAG
//     ORDER with the key-slot PERMUTATION matching the QK^T C-layout:
//     in-chunk key p = 4h' + a + 8b' -> va-group p>>4, lane-half h'=(p>>2)&1,
//     element j = 4*((p>>3)&1) + (p&3). Plus pad rows m=16..31 (m==16 -> 1.0
//     ones-row for the l-accumulator trick).
// ---------------------------------------------------------------------------
__global__ __launch_bounds__(512, 4) void qkv_kernel(
    const float* __restrict__ x,
    const float* __restrict__ Wq, const float* __restrict__ Wk,
    const float* __restrict__ Wv,
    f16* __restrict__ qo, f16* __restrict__ ko, f16* __restrict__ vo)
{
    constexpr int LDW = 136;                      // padded row (f16), b128-aligned
    __shared__ __align__(16) f16 Xs[32 * LDW];    // 8.7 KB

    const int rowbase = blockIdx.x * 32;

    // stage X tile (32 x 128) fp32 -> f16, coalesced float4 reads (ONCE)
    for (int idx = threadIdx.x; idx < 32 * 32; idx += 512) {
        const int r = idx >> 5, cp = idx & 31;
        float4 v = *(const float4*)(x + (size_t)(rowbase + r) * Ee + cp * 4);
        union { f16 h[4]; uint2 u; } cv;
        cv.h[0] = (f16)v.x; cv.h[1] = (f16)v.y; cv.h[2] = (f16)v.z; cv.h[3] = (f16)v.w;
        *(uint2*)&Xs[r * LDW + cp * 4] = cv.u;
    }
    __syncthreads();

    const int wid = threadIdx.x >> 6, lane = threadIdx.x & 63;
    const int h = lane >> 5, n31 = lane & 31;

    // per-lane 16B X fragments (same bytes serve as A- or B-operand)
    f16x8 Xf[8];
#pragma unroll
    for (int t = 0; t < 8; ++t)
        Xf[t] = *(const f16x8*)&Xs[n31 * LDW + 16 * t + 8 * h];

    const int b = rowbase >> 11;
    const int s0 = rowbase & 2047;

    if (wid < 4) {
        // ---- Q and K, swapped operands: C[c][s], channels in regs ----
        const int s = s0 + n31;
#pragma unroll
        for (int mat = 0; mat < 2; ++mat) {
            const float* W = (mat == 0) ? Wq : Wk;
            const float* wr32 = W + (size_t)(wid * 32 + n31) * Ee + 8 * h;
            f32x16 acc = {};
#pragma unroll
            for (int t = 0; t < 8; ++t) {
                float4 w0 = *(const float4*)(wr32 + 16 * t);
                float4 w1 = *(const float4*)(wr32 + 16 * t + 4);
                acc = __builtin_amdgcn_mfma_f32_32x32x16_f16(cvt8(w0, w1), Xf[t], acc, 0, 0, 0);
            }
            f16* dst = (mat == 0) ? qo : ko;
            const float scale = (mat == 1) ? QSCALE : 1.f;
#pragma unroll
            for (int rq = 0; rq < 4; ++rq) {
                const int cbase = wid * 32 + 8 * rq + 4 * h;   // 4 consecutive c
                const int head = cbase >> 4, dbase = cbase & 15;
                union { f16 hv[4]; uint2 u; } pk4;
#pragma unroll
                for (int i = 0; i < 4; ++i) pk4.hv[i] = (f16)(acc[4 * rq + i] * scale);
                *(uint2*)(dst + ((size_t)(b * Hh + head) * Ss + s) * HSs + dbase) = pk4.u;
            }
        }
    } else {
        // ---- V, original order: C[s][c], key-slots in regs ----
        const int g = wid - 4;
        const int c = g * 32 + n31;               // channel = head*16 + d
        const int head = c >> 4, d = c & 15;
        const int bh = b * Hh + head;
        const int it = s0 >> 6, g0 = (s0 >> 4) & 3;
        const float* wr32 = Wv + (size_t)c * Ee + 8 * h;
        f32x16 acc = {};
#pragma unroll
        for (int t = 0; t < 8; ++t) {
            float4 w0 = *(const float4*)(wr32 + 16 * t);
            float4 w1 = *(const float4*)(wr32 + 16 * t + 4);
            acc = __builtin_amdgcn_mfma_f32_32x32x16_f16(Xf[t], cvt8(w0, w1), acc, 0, 0, 0);
        }
        f16* vb = vo + (size_t)bh * 65536 + it * 2048;
#pragma unroll
        for (int rq = 0; rq < 4; ++rq) {
            union { f16 hv[4]; uint2 u; } pk4;
#pragma unroll
            for (int i = 0; i < 4; ++i) pk4.hv[i] = (f16)acc[4 * rq + i];
            // permuted k-slot placement: h' = h, b' = rq&1, j = 4*b' + a
            *(uint2*)(vb + (g0 + (rq >> 1)) * 512 + (d + 32 * h) * 8 + 4 * (rq & 1)) = pk4.u;
        }

        // pad rows m=16..31 for this block's two 16-key groups, all 8 heads:
        // m==16 -> 1.0 (l-accumulator row), else 0. All k-slots equal.
        for (int i = threadIdx.x - 256; i < 512; i += 256) {
            const int gp = i >> 8, hd = (i >> 5) & 7, cc = i & 31;
            const int lanep = (cc < 16) ? 16 + cc : 32 + cc;
            const unsigned one2 = 0x3C003C00u;
            uint4 val = ((cc & 15) == 0) ? (uint4){one2, one2, one2, one2}
                                         : (uint4){0, 0, 0, 0};
            *(uint4*)(vo + (size_t)(b * Hh + hd) * 65536 + it * 2048
                      + (g0 + gp) * 512 + lanep * 8) = val;
        }
    }
}

// ---------------------------------------------------------------------------
// Kernel B: FUSED flash attention + output projection. 512 blocks x 8 waves;
// wave = one head, block = all 8 heads of one (batch, 32-query) tile.
// REGISTER-DIET LOOP: 32-key chunks (1 QK MFMA -> 16-val max3 tree ->
// per-16-key-group {16 exp2 -> 4 pack -> PV MFMA} interleave). Halves score
// liveness vs 64-key chunks, removes B-array liveness, and overlaps PV MFMA
// execution with the next group's exp2s (trans pipe).  __launch_bounds__
// (512,4) caps total regs at 128 -> 2 blocks/CU = 16 waves/CU.
//   - V key-slot permutation => P feeds PV with zero cross-lane exchange;
//     ones-row at m=16 accumulates l into acc[8] (h=0 half).
//   - running max folded into QK^T C-operand (cinit = -m); deferred rescale
//     THR=8 via wave-uniform __any.
//   - ka prefetched one chunk ahead in place; va loaded at chunk top
//     (~280 trans-cycles before its PV use).
//   - epilogue: normalized O -> LDS tile [32 x 136]; one barrier; waves 0..3
//     do proj (K=128, 8 MFMA) with inline fp32->f16 Wp cvt, fp32+bias stores.
// XCD swizzle: b = blk&7 -> each batch's K/V pinned to one XCD L2.
// ---------------------------------------------------------------------------
__global__ __launch_bounds__(512, 4) void attn_kernel(
    const f16* __restrict__ qg, const f16* __restrict__ kg,
    const f16* __restrict__ vg, const float* __restrict__ wp32,
    const float* __restrict__ bp, float* __restrict__ out)
{
    constexpr int LDW = 136;
    __shared__ __align__(16) f16 Os[32 * LDW];    // 8.7 KB

    const int b    = blockIdx.x & 7;               // XCD-local batches
    const int qblk = blockIdx.x >> 3;
    const int wid  = threadIdx.x >> 6;             // head
    const int lane = threadIdx.x & 63;
    const int h    = lane >> 5;
    const int q31  = lane & 31;
    const int qbase = qblk * 32;
    const int bh   = b * Hh + wid;

    // Q B-frag (QSCALE folded into k)
    const f16x8 qf = *(const f16x8*)(qg + ((size_t)bh * Ss + qbase + q31) * HSs + 8 * h);

    // per-lane streaming pointers (16B/lane contiguous, coalesced per wave)
    const f16* pk = kg + (size_t)bh * Ss * HSs + q31 * 16 + 8 * h;
    const f16* pv = vg + (size_t)bh * 65536 + lane * 8;

    f16x8 ka = *(const f16x8*)pk;                  // current 32-key K tile

    f32x16 acc = {};
    f32x16 cinit = {};                 // broadcast -m; st = s - m straight from MFMA

    constexpr int NCH = Ss / 32;       // 64 chunks of 32 keys
    for (int c = 0; c < NCH; ++c) {
        // va pair for this chunk: issued early, consumed after the exps
        const f16* pvc = pv + (size_t)c * 1024;
        f16x8 va0 = *(const f16x8*)(pvc);
        f16x8 va1 = *(const f16x8*)(pvc + 512);

        // S^T - m = K x Q^T + cinit for this chunk's 32 keys
        f32x16 st = __builtin_amdgcn_mfma_f32_32x32x16_f16(ka, qf, cinit, 0, 0, 0);

        // K operand dead: prefetch next chunk in place
        if (c + 1 < NCH) ka = *(const f16x8*)(pk + (c + 1) * 512);

        // chunk max relative to m (max3 tree + one xor32)
        float mx = vmax16(st);
        mx = fmaxf(mx, __shfl_xor(mx, 32, 64));

        // deferred rescale: only when some query grew past m + 8
        if (__any(mx > 8.f)) {
            const float delta = fmaxf(mx, 0.f);
            const float corr  = __builtin_amdgcn_exp2f(-delta);
#pragma unroll
            for (int r = 0; r < 9; ++r) acc[r] *= corr;   // d regs + l in acc[8]
#pragma unroll
            for (int t = 0; t < 16; ++t) st[t] -= delta;
#pragma unroll
            for (int r = 0; r < 16; ++r) cinit[r] -= delta;
        }

        // group 0 (keys 0..15): exp2 -> pack -> PV MFMA
        {
            union { unsigned u[4]; f16x8 v; } B;
#pragma unroll
            for (int r = 0; r < 4; ++r)
                B.u[r] = pack_rtz(__builtin_amdgcn_exp2f(st[2 * r]),
                                  __builtin_amdgcn_exp2f(st[2 * r + 1]));
            __builtin_amdgcn_s_setprio(1);
            acc = __builtin_amdgcn_mfma_f32_32x32x16_f16(va0, B.v, acc, 0, 0, 0);
            __builtin_amdgcn_s_setprio(0);
        }
        // group 1 (keys 16..31): exps overlap group 0's MFMA execution
        {
            union { unsigned u[4]; f16x8 v; } B;
#pragma unroll
            for (int r = 0; r < 4; ++r)
                B.u[r] = pack_rtz(__builtin_amdgcn_exp2f(st[8 + 2 * r]),
                                  __builtin_amdgcn_exp2f(st[9 + 2 * r]));
            __builtin_amdgcn_s_setprio(1);
            acc = __builtin_amdgcn_mfma_f32_32x32x16_f16(va1, B.v, acc, 0, 0, 0);
            __builtin_amdgcn_s_setprio(0);
        }
    }

    // l lives in acc[8] of the h=0 half (row 16); h=1 half's acc[8] is 0
    const float l = acc[8] + __shfl_xor(acc[8], 32, 64);
    const float inv = 1.f / l;

    // normalized O fragment (head's 8 channels for query q31) -> LDS tile
    f16* orow = &Os[q31 * LDW + wid * HSs + 4 * h];
    uint2 lo = { pack_rne(acc[0] * inv, acc[1] * inv), pack_rne(acc[2] * inv, acc[3] * inv) };
    uint2 hi = { pack_rne(acc[4] * inv, acc[5] * inv), pack_rne(acc[6] * inv, acc[7] * inv) };
    *(uint2*)(orow)     = lo;
    *(uint2*)(orow + 8) = hi;
    __syncthreads();

    if (wid >= 4) return;

    // ---- output projection: waves 0..3, one 32-channel group each ----
    f16x8 A[8];
#pragma unroll
    for (int t = 0; t < 8; ++t)
        A[t] = *(const f16x8*)&Os[q31 * LDW + 16 * t + 8 * h];

    const int e = wid * 32 + q31;
    const float* wr32 = wp32 + (size_t)e * Ee + 8 * h;
    f32x16 acc2 = {};
#pragma unroll
    for (int t = 0; t < 8; ++t) {
        float4 w0 = *(const float4*)(wr32 + 16 * t);
        float4 w1 = *(const float4*)(wr32 + 16 * t + 4);
        acc2 = __builtin_amdgcn_mfma_f32_32x32x16_f16(A[t], cvt8(w0, w1), acc2, 0, 0, 0);
    }

    const float bias = bp[e];
#pragma unroll
    for (int r = 0; r < 16; ++r) {
        const int R = qbase + (r & 3) + 8 * (r >> 2) + 4 * h;
        out[((size_t)b * Ss + R) * Ee + e] = acc2[r] + bias;
    }
}

// ---------------------------------------------------------------------------
extern "C" void kernel_launch(void* const* d_in, const int* in_sizes, int n_in,
                              void* d_out, int out_size, void* d_ws, size_t ws_size,
                              hipStream_t stream)
{
    const float* x  = (const float*)d_in[0];
    const float* Wk = (const float*)d_in[1];
    const float* Wq = (const float*)d_in[2];
    const float* Wv = (const float*)d_in[3];
    const float* Wp = (const float*)d_in[4];
    const float* bp = (const float*)d_in[5];
    float* out = (float*)d_out;

    f16* ws = (f16*)d_ws;
    f16* qh = ws;                            // 2M f16
    f16* kh = ws + (size_t)QKVSZ;            // 2M
    f16* vh = ws + (size_t)2 * QKVSZ;        // 4M (A-frag order + pad rows, permuted k-slots)

    qkv_kernel<<<Bb * Ss / 32, 512, 0, stream>>>(x, Wq, Wk, Wv, qh, kh, vh);
    attn_kernel<<<Bb * Ss / 32, 512, 0, stream>>>(qh, kh, vh, Wp, bp, out);
}

// Round 7
// 132.250 us; speedup vs baseline: 1.0551x; 1.0112x over previous
//
#include <hip/hip_runtime.h>
#include <hip/hip_bf16.h>

// Problem constants
constexpr int Bb  = 8;
constexpr int Ss  = 2048;
constexpr int Ee  = 128;
constexpr int Hh  = 8;
constexpr int HSs = 16;
constexpr int QKVSZ = Bb * Hh * Ss * HSs;  // 2,097,152 elements per tensor

typedef _Float16 f16;
typedef __attribute__((ext_vector_type(8)))  _Float16 f16x8;   // 8 f16 = 4 VGPRs
typedef __attribute__((ext_vector_type(16))) float f32x16;

constexpr float QSCALE = 5.770780163555854f;  // 4 * log2(e); folded into stored k

// RTZ packed fp32x2 -> fp16x2
__device__ __forceinline__ unsigned pack_rtz(float lo, float hi) {
    union { __fp16 __attribute__((ext_vector_type(2))) h; unsigned u; } c;
    c.h = __builtin_amdgcn_cvt_pkrtz(lo, hi);
    return c.u;
}
// RNE pair pack
__device__ __forceinline__ unsigned pack_rne(float lo, float hi) {
    union { __attribute__((ext_vector_type(2))) _Float16 h; unsigned u; } c;
    c.h[0] = (f16)lo; c.h[1] = (f16)hi;
    return c.u;
}

// max of 16 floats, max3-friendly groupings (ISel fuses fmax(fmax(a,b),c) -> v_max3_f32)
__device__ __forceinline__ float vmax16(const f32x16& v) {
    float a = fmaxf(fmaxf(v[0],  v[1]),  v[2]);
    float b = fmaxf(fmaxf(v[3],  v[4]),  v[5]);
    float c = fmaxf(fmaxf(v[6],  v[7]),  v[8]);
    float d = fmaxf(fmaxf(v[9],  v[10]), v[11]);
    float e = fmaxf(fmaxf(v[12], v[13]), v[14]);
    float g = fmaxf(fmaxf(a, b), c);
    float h = fmaxf(fmaxf(d, e), v[15]);
    return fmaxf(g, h);
}

// fp32x8 -> f16x8 (RNE) from two float4s
__device__ __forceinline__ f16x8 cvt8(const float4& w0, const float4& w1) {
    union { f16x8 v; unsigned u[4]; } wf;
    wf.u[0] = pack_rne(w0.x, w0.y); wf.u[1] = pack_rne(w0.z, w0.w);
    wf.u[2] = pack_rne(w1.x, w1.y); wf.u[3] = pack_rne(w1.z, w1.w);
    return wf.v;
}

// ---------------------------------------------------------------------------
// Kernel A: FUSED Q/K/V projection, 8 waves (512 thr), inline fp32->f16 W cvt.
// X staged fp32->f16 via LDS ONCE; the same per-lane 16B fragment serves as
// B-operand (waves 0-3, q/k, SWAPPED operand order) and A-operand (waves 4-7,
// v, original order) -- A and B per-lane layouts are identical.
//   waves 0-3 (wid=0..3): Q then K for channel group wid, C[c][s] layout ->
//     channels in regs, rows in lanes -> uint2 (4 x f16 consecutive d) stores.
//   waves 4-7: V group wid-4, original order C[s][c]; v written in A-FRAG
//     ORDER with the key-slot PERMUTATION matching the QK^T C-layout:
//     in-chunk key p = 4h' + a + 8b' -> va-group p>>4, lane-half h'=(p>>2)&1,
//     element j = 4*((p>>3)&1) + (p&3). Plus pad rows m=16..31 (m==16 -> 1.0
//     ones-row for the l-accumulator trick).
// ---------------------------------------------------------------------------
__global__ __launch_bounds__(512, 4) void qkv_kernel(
    const float* __restrict__ x,
    const float* __restrict__ Wq, const float* __restrict__ Wk,
    const float* __restrict__ Wv,
    f16* __restrict__ qo, f16* __restrict__ ko, f16* __restrict__ vo)
{
    constexpr int LDW = 136;                      // padded row (f16), b128-aligned
    __shared__ __align__(16) f16 Xs[32 * LDW];    // 8.7 KB

    const int rowbase = blockIdx.x * 32;

    // stage X tile (32 x 128) fp32 -> f16, coalesced float4 reads (ONCE)
    for (int idx = threadIdx.x; idx < 32 * 32; idx += 512) {
        const int r = idx >> 5, cp = idx & 31;
        float4 v = *(const float4*)(x + (size_t)(rowbase + r) * Ee + cp * 4);
        union { f16 h[4]; uint2 u; } cv;
        cv.h[0] = (f16)v.x; cv.h[1] = (f16)v.y; cv.h[2] = (f16)v.z; cv.h[3] = (f16)v.w;
        *(uint2*)&Xs[r * LDW + cp * 4] = cv.u;
    }
    __syncthreads();

    const int wid = threadIdx.x >> 6, lane = threadIdx.x & 63;
    const int h = lane >> 5, n31 = lane & 31;

    // per-lane 16B X fragments (same bytes serve as A- or B-operand)
    f16x8 Xf[8];
#pragma unroll
    for (int t = 0; t < 8; ++t)
        Xf[t] = *(const f16x8*)&Xs[n31 * LDW + 16 * t + 8 * h];

    const int b = rowbase >> 11;
    const int s0 = rowbase & 2047;

    if (wid < 4) {
        // ---- Q and K, swapped operands: C[c][s], channels in regs ----
        const int s = s0 + n31;
#pragma unroll
        for (int mat = 0; mat < 2; ++mat) {
            const float* W = (mat == 0) ? Wq : Wk;
            const float* wr32 = W + (size_t)(wid * 32 + n31) * Ee + 8 * h;
            f32x16 acc = {};
#pragma unroll
            for (int t = 0; t < 8; ++t) {
                float4 w0 = *(const float4*)(wr32 + 16 * t);
                float4 w1 = *(const float4*)(wr32 + 16 * t + 4);
                acc = __builtin_amdgcn_mfma_f32_32x32x16_f16(cvt8(w0, w1), Xf[t], acc, 0, 0, 0);
            }
            f16* dst = (mat == 0) ? qo : ko;
            const float scale = (mat == 1) ? QSCALE : 1.f;
#pragma unroll
            for (int rq = 0; rq < 4; ++rq) {
                const int cbase = wid * 32 + 8 * rq + 4 * h;   // 4 consecutive c
                const int head = cbase >> 4, dbase = cbase & 15;
                union { f16 hv[4]; uint2 u; } pk4;
#pragma unroll
                for (int i = 0; i < 4; ++i) pk4.hv[i] = (f16)(acc[4 * rq + i] * scale);
                *(uint2*)(dst + ((size_t)(b * Hh + head) * Ss + s) * HSs + dbase) = pk4.u;
            }
        }
    } else {
        // ---- V, original order: C[s][c], key-slots in regs ----
        const int g = wid - 4;
        const int c = g * 32 + n31;               // channel = head*16 + d
        const int head = c >> 4, d = c & 15;
        const int bh = b * Hh + head;
        const int it = s0 >> 6, g0 = (s0 >> 4) & 3;
        const float* wr32 = Wv + (size_t)c * Ee + 8 * h;
        f32x16 acc = {};
#pragma unroll
        for (int t = 0; t < 8; ++t) {
            float4 w0 = *(const float4*)(wr32 + 16 * t);
            float4 w1 = *(const float4*)(wr32 + 16 * t + 4);
            acc = __builtin_amdgcn_mfma_f32_32x32x16_f16(Xf[t], cvt8(w0, w1), acc, 0, 0, 0);
        }
        f16* vb = vo + (size_t)bh * 65536 + it * 2048;
#pragma unroll
        for (int rq = 0; rq < 4; ++rq) {
            union { f16 hv[4]; uint2 u; } pk4;
#pragma unroll
            for (int i = 0; i < 4; ++i) pk4.hv[i] = (f16)acc[4 * rq + i];
            // permuted k-slot placement: h' = h, b' = rq&1, j = 4*b' + a
            *(uint2*)(vb + (g0 + (rq >> 1)) * 512 + (d + 32 * h) * 8 + 4 * (rq & 1)) = pk4.u;
        }

        // pad rows m=16..31 for this block's two 16-key groups, all 8 heads:
        // m==16 -> 1.0 (l-accumulator row), else 0. All k-slots equal.
        for (int i = threadIdx.x - 256; i < 512; i += 256) {
            const int gp = i >> 8, hd = (i >> 5) & 7, cc = i & 31;
            const int lanep = (cc < 16) ? 16 + cc : 32 + cc;
            const unsigned one2 = 0x3C003C00u;
            uint4 val = ((cc & 15) == 0) ? (uint4){one2, one2, one2, one2}
                                         : (uint4){0, 0, 0, 0};
            *(uint4*)(vo + (size_t)(b * Hh + hd) * 65536 + it * 2048
                      + (g0 + gp) * 512 + lanep * 8) = val;
        }
    }
}

// ---------------------------------------------------------------------------
// chunk_step: one software-pipelined 32-key chunk.
// On entry: stC/mxC = this chunk's scores (rel. to current m) + their max;
//           kaN = K-frag of the NEXT chunk; vaC0/vaC1 = V of THIS chunk.
// Does: rescale-if-needed (updates cinit) -> issue NEXT chunk's QK MFMA with
// the updated cinit -> prefetch K(+2)/V(+1) into dead regs -> exp/pack/PV of
// THIS chunk (overlapping the in-flight QK) -> max tree of the NEXT chunk
// (QK latency fully hidden under the exps).
// ---------------------------------------------------------------------------
__device__ __forceinline__ void chunk_step(
    f32x16& stC, float& mxC, f32x16& stN, float& mxN,
    const f16x8 kaN, const f16x8 vaC0, const f16x8 vaC1,
    f16x8& kaN2, f16x8& vaN0, f16x8& vaN1,
    const f16* __restrict__ pkN2, const f16* __restrict__ pvN,
    f32x16& acc, f32x16& cinit, const f16x8 qf)
{
    // deferred rescale: only when some query grew past m + 8
    if (__any(mxC > 8.f)) {
        const float delta = fmaxf(mxC, 0.f);
        const float corr  = __builtin_amdgcn_exp2f(-delta);
#pragma unroll
        for (int r = 0; r < 9; ++r) acc[r] *= corr;   // d regs + l in acc[8]
#pragma unroll
        for (int t = 0; t < 16; ++t) stC[t] -= delta;
#pragma unroll
        for (int r = 0; r < 16; ++r) cinit[r] -= delta;
    }

    // NEXT chunk's scores: S^T - m = K x Q^T + cinit (post-rescale cinit)
    stN = __builtin_amdgcn_mfma_f32_32x32x16_f16(kaN, qf, cinit, 0, 0, 0);

    // prefetch into dead registers: K two chunks ahead, V one chunk ahead
    kaN2 = *(const f16x8*)pkN2;
    vaN0 = *(const f16x8*)(pvN);
    vaN1 = *(const f16x8*)(pvN + 512);

    // THIS chunk's softmax + PV (overlaps the QK MFMA above)
    union { unsigned u[4]; f16x8 v; } B0, B1;
#pragma unroll
    for (int r = 0; r < 4; ++r)
        B0.u[r] = pack_rtz(__builtin_amdgcn_exp2f(stC[2 * r]),
                           __builtin_amdgcn_exp2f(stC[2 * r + 1]));
#pragma unroll
    for (int r = 0; r < 4; ++r)
        B1.u[r] = pack_rtz(__builtin_amdgcn_exp2f(stC[8 + 2 * r]),
                           __builtin_amdgcn_exp2f(stC[9 + 2 * r]));
    __builtin_amdgcn_s_setprio(1);
    acc = __builtin_amdgcn_mfma_f32_32x32x16_f16(vaC0, B0.v, acc, 0, 0, 0);
    acc = __builtin_amdgcn_mfma_f32_32x32x16_f16(vaC1, B1.v, acc, 0, 0, 0);
    __builtin_amdgcn_s_setprio(0);

    // NEXT chunk's max (max3 tree + one xor32) — QK latency hidden by now
    float m16 = vmax16(stN);
    mxN = fmaxf(m16, __shfl_xor(m16, 32, 64));
}

// ---------------------------------------------------------------------------
// Kernel B: FUSED flash attention + output projection. 512 blocks x 8 waves;
// wave = one head, block = all 8 heads of one (batch, 32-query) tile.
// SOFTWARE-PIPELINED 32-key chunks: the max-tree/shfl/__any segment of chunk
// c+1 is computed UNDER chunk c's exp/pack/PV, removing ~150 cyc of serial
// latency per chunk (the measured per-chunk wall was ~525 cyc vs ~190 issue).
//   - V key-slot permutation => P feeds PV with zero cross-lane exchange;
//     ones-row at m=16 accumulates l into acc[8] (h=0 half).
//   - running max folded into QK^T C-operand (cinit = -m); deferred rescale
//     THR=8 via wave-uniform __any, tested one chunk late (lag is exact:
//     QK(c+1) issues after rescale(c) with updated cinit).
//   - K prefetched 2 chunks ahead, V 1 ahead, all into dead registers.
//     Tail over-reads land in allocated workspace and are never consumed.
//   - epilogue: normalized O -> LDS tile [32 x 136]; one barrier; waves 0..3
//     do proj (K=128, 8 MFMA) with inline fp32->f16 Wp cvt, fp32+bias stores.
// XCD swizzle: b = blk&7 -> each batch's K/V pinned to one XCD L2.
// ---------------------------------------------------------------------------
__global__ __launch_bounds__(512, 4) void attn_kernel(
    const f16* __restrict__ qg, const f16* __restrict__ kg,
    const f16* __restrict__ vg, const float* __restrict__ wp32,
    const float* __restrict__ bp, float* __restrict__ out)
{
    constexpr int LDW = 136;
    __shared__ __align__(16) f16 Os[32 * LDW];    // 8.7 KB

    const int b    = blockIdx.x & 7;               // XCD-local batches
    const int qblk = blockIdx.x >> 3;
    const int wid  = threadIdx.x >> 6;             // head
    const int lane = threadIdx.x & 63;
    const int h    = lane >> 5;
    const int q31  = lane & 31;
    const int qbase = qblk * 32;
    const int bh   = b * Hh + wid;

    // Q B-frag (QSCALE folded into k)
    const f16x8 qf = *(const f16x8*)(qg + ((size_t)bh * Ss + qbase + q31) * HSs + 8 * h);

    // per-lane streaming pointers (16B/lane contiguous, coalesced per wave)
    const f16* pk = kg + (size_t)bh * Ss * HSs + q31 * 16 + 8 * h;
    const f16* pv = vg + (size_t)bh * 65536 + lane * 8;

    f32x16 acc = {};
    f32x16 cinit = {};                 // broadcast -m; st = s - m straight from MFMA

    // pipeline state
    f32x16 stA, stB;
    float mxA, mxB;
    f16x8 kaN, kaN2, vaC0, vaC1, vaN0, vaN1;

    // prologue: chunk 0 scores + max; K[1]; V[0]
    {
        f16x8 ka0 = *(const f16x8*)pk;
        kaN  = *(const f16x8*)(pk + 512);
        vaC0 = *(const f16x8*)(pv);
        vaC1 = *(const f16x8*)(pv + 512);
        stA  = __builtin_amdgcn_mfma_f32_32x32x16_f16(ka0, qf, cinit, 0, 0, 0);
        float m16 = vmax16(stA);
        mxA = fmaxf(m16, __shfl_xor(m16, 32, 64));
    }

    constexpr int NCH = Ss / 32;       // 64 chunks of 32 keys
    for (int c = 0; c < NCH; c += 2) {
        chunk_step(stA, mxA, stB, mxB, kaN, vaC0, vaC1,
                   kaN2, vaN0, vaN1,
                   pk + (size_t)(c + 2) * 512, pv + (size_t)(c + 1) * 1024,
                   acc, cinit, qf);
        chunk_step(stB, mxB, stA, mxA, kaN2, vaN0, vaN1,
                   kaN, vaC0, vaC1,
                   pk + (size_t)(c + 3) * 512, pv + (size_t)(c + 2) * 1024,
                   acc, cinit, qf);
    }

    // l lives in acc[8] of the h=0 half (row 16); h=1 half's acc[8] is 0
    const float l = acc[8] + __shfl_xor(acc[8], 32, 64);
    const float inv = 1.f / l;

    // normalized O fragment (head's 8 channels for query q31) -> LDS tile
    f16* orow = &Os[q31 * LDW + wid * HSs + 4 * h];
    uint2 lo = { pack_rne(acc[0] * inv, acc[1] * inv), pack_rne(acc[2] * inv, acc[3] * inv) };
    uint2 hi = { pack_rne(acc[4] * inv, acc[5] * inv), pack_rne(acc[6] * inv, acc[7] * inv) };
    *(uint2*)(orow)     = lo;
    *(uint2*)(orow + 8) = hi;
    __syncthreads();

    if (wid >= 4) return;

    // ---- output projection: waves 0..3, one 32-channel group each ----
    f16x8 A[8];
#pragma unroll
    for (int t = 0; t < 8; ++t)
        A[t] = *(const f16x8*)&Os[q31 * LDW + 16 * t + 8 * h];

    const int e = wid * 32 + q31;
    const float* wr32 = wp32 + (size_t)e * Ee + 8 * h;
    f32x16 acc2 = {};
#pragma unroll
    for (int t = 0; t < 8; ++t) {
        float4 w0 = *(const float4*)(wr32 + 16 * t);
        float4 w1 = *(const float4*)(wr32 + 16 * t + 4);
        acc2 = __builtin_amdgcn_mfma_f32_32x32x16_f16(A[t], cvt8(w0, w1), acc2, 0, 0, 0);
    }

    const float bias = bp[e];
#pragma unroll
    for (int r = 0; r < 16; ++r) {
        const int R = qbase + (r & 3) + 8 * (r >> 2) + 4 * h;
        out[((size_t)b * Ss + R) * Ee + e] = acc2[r] + bias;
    }
}

// ---------------------------------------------------------------------------
extern "C" void kernel_launch(void* const* d_in, const int* in_sizes, int n_in,
                              void* d_out, int out_size, void* d_ws, size_t ws_size,
                              hipStream_t stream)
{
    const float* x  = (const float*)d_in[0];
    const float* Wk = (const float*)d_in[1];
    const float* Wq = (const float*)d_in[2];
    const float* Wv = (const float*)d_in[3];
    const float* Wp = (const float*)d_in[4];
    const float* bp = (const float*)d_in[5];
    float* out = (float*)d_out;

    f16* ws = (f16*)d_ws;
    f16* qh = ws;                            // 2M f16
    f16* kh = ws + (size_t)QKVSZ;            // 2M
    f16* vh = ws + (size_t)2 * QKVSZ;        // 4M (A-frag order + pad rows, permuted k-slots)

    qkv_kernel<<<Bb * Ss / 32, 512, 0, stream>>>(x, Wq, Wk, Wv, qh, kh, vh);
    attn_kernel<<<Bb * Ss / 32, 512, 0, stream>>>(qh, kh, vh, Wp, bp, out);
}